// Round 3
// baseline (6007.623 us; speedup 1.0000x reference)
//
#include <hip/hip_runtime.h>
#include <hip/hip_bf16.h>

// GraphMoE dual router: encoder -> routers -> 8 GraphConv experts (3 layers) -> sparse combine.
// R1: agg latency fix (163->~100us). R2:
//  - agg v3: XCD-sliced gather (slice = blockIdx.x & 7 -> one 3.2 MB Z column slice per XCD's L2),
//    wave per (node,slice), 4 quarter-waves over edges, shfl reduce, nontemporal cols stream.
//  - top-2 sparsity: per-expert selected lists; layer-1->2 agg and layer-2 GEMM only on
//    selected rows (4x less work); out = memset + non-atomic += across sequential expert launches.
//  - cols as ushort (halves scatter partial-line writes); hist via outdeg (no random gathers).

#define NN 50000
#define EE 1600000
#define GG 64
#define HH 256
#define NEXP 8
#define LAY 3
#define KD 512          // concat K = [z | agg]
#define MT 128          // GEMM row tile per block
#define BK 64           // GEMM K tile
#define LST 72          // padded LDS stride (elements): 16B-aligned, bank-balanced

typedef __attribute__((ext_vector_type(8))) short bf16x8;
typedef __attribute__((ext_vector_type(8))) unsigned short u16x8;
typedef __attribute__((ext_vector_type(4))) float f32x4;

__device__ __forceinline__ float bf2f(unsigned short u) {
    union { unsigned int i; float f; } v; v.i = ((unsigned int)u) << 16; return v.f;
}
__device__ __forceinline__ unsigned short f2bf(float f) {
    union { unsigned int i; float f; } v; v.f = f;
    unsigned int r = (v.i + 0x7FFFu + ((v.i >> 16) & 1u)) >> 16;
    return (unsigned short)r;
}

// ---------------- encoder: h = relu(x[:,4:10] @ W_enc + b_enc), bf16 into Ash cols 0..255
__global__ void encoder_kernel(const float* __restrict__ x, const float* __restrict__ W,
                               const float* __restrict__ b, unsigned short* __restrict__ out) {
    int n = blockIdx.x, j = threadIdx.x;
    float acc = b[j];
#pragma unroll
    for (int i = 0; i < 6; i++) acc += x[n * 10 + 4 + i] * W[i * HH + j];
    acc = fmaxf(acc, 0.f);
    out[(long)n * KD + j] = f2bf(acc);
}

// ---------------- weight packing: Bt[(e*3+l)][n][k] bf16, k<256 -> W_self, k>=256 -> W_neigh
__global__ void pack_experts(const float* __restrict__ Wself, const float* __restrict__ Wneigh,
                             unsigned short* __restrict__ Bt) {
    int idx = blockIdx.x * 256 + threadIdx.x;          // (e,l,k,n), n fastest
    int n = idx & 255; int r = idx >> 8;
    int k = r & 511; r >>= 9;
    int l = r % LAY; int e = r / LAY;
    float v = (k < 256) ? Wself[(((e * LAY + l) * HH) + k) * HH + n]
                        : Wneigh[(((e * LAY + l) * HH) + (k - 256)) * HH + n];
    Bt[(((long)(e * LAY + l) * HH + n) * KD) + k] = f2bf(v);
}

__global__ void pack_ws1(const float* __restrict__ W, unsigned short* __restrict__ Bt) {
    int idx = blockIdx.x * 256 + threadIdx.x;
    int n = idx & 255; int k = idx >> 8;
    Bt[(long)n * HH + k] = f2bf(W[k * HH + n]);
}

// ---------------- degree pass: indeg (CSR rows) + outdeg (for per-graph edge histogram)
__global__ void deg_kernel(const int* __restrict__ src, const int* __restrict__ dst,
                           int* __restrict__ deg, int* __restrict__ outdeg) {
    int e = blockIdx.x * 256 + threadIdx.x;
    if (e < EE) {
        atomicAdd(&deg[dst[e]], 1);
        atomicAdd(&outdeg[src[e]], 1);
    }
}

// ---------------- per-graph node/edge histograms from sorted batch + outdeg (coalesced)
__global__ void hist_kernel(const int* __restrict__ batch, const int* __restrict__ outdeg,
                            int* __restrict__ ncnt, int* __restrict__ ecnt) {
    __shared__ int hn[GG], he[GG];
    if (threadIdx.x < GG) { hn[threadIdx.x] = 0; he[threadIdx.x] = 0; }
    __syncthreads();
    int i = blockIdx.x * 256 + threadIdx.x;
    if (i < NN) {
        int g = batch[i];
        atomicAdd(&hn[g], 1);
        atomicAdd(&he[g], outdeg[i]);
    }
    __syncthreads();
    if (threadIdx.x < GG) {
        if (hn[threadIdx.x]) atomicAdd(&ncnt[threadIdx.x], hn[threadIdx.x]);
        if (he[threadIdx.x]) atomicAdd(&ecnt[threadIdx.x], he[threadIdx.x]);
    }
}

// ---------------- structural router per graph: stru = relu(feat@Wt1+bt1)@Wt2+bt2
__global__ void stru_kernel(const int* __restrict__ ncnt, const int* __restrict__ ecnt,
                            const float* __restrict__ Wt1, const float* __restrict__ bt1,
                            const float* __restrict__ Wt2, const float* __restrict__ bt2,
                            float* __restrict__ strug) {
    __shared__ float t[HH];
    int g = blockIdx.x, j = threadIdx.x;
    float nf = log1pf((float)ncnt[g]);
    float ef = log1pf((float)ecnt[g]);
    float v = nf * Wt1[j] + ef * Wt1[HH + j] + bt1[j];
    t[j] = fmaxf(v, 0.f);
    __syncthreads();
    if (j < 8) {
        float sum = bt2[j];
        for (int k = 0; k < HH; k++) sum += t[k] * Wt2[k * 8 + j];
        strug[g * 8 + j] = sum;
    }
}

// single block, 1024 threads; shuffle-based inclusive scan, 2 barriers per 1024-chunk
__global__ void scan_kernel(const int* __restrict__ deg, int* __restrict__ rowstart,
                            int* __restrict__ cursor) {
    __shared__ int wsum[16];
    __shared__ int carry_s;
    int tid = threadIdx.x;
    int wid = tid >> 6, lane = tid & 63;
    if (tid == 0) carry_s = 0;
    __syncthreads();
    for (int base = 0; base < NN; base += 1024) {
        int i = base + tid;
        int v = (i < NN) ? deg[i] : 0;
        int sc = v;
#pragma unroll
        for (int off = 1; off < 64; off <<= 1) {
            int t = __shfl_up(sc, off, 64);
            if (lane >= off) sc += t;
        }
        if (lane == 63) wsum[wid] = sc;
        __syncthreads();
        int carry = carry_s;
        int prev = 0;
        for (int w = 0; w < wid; w++) prev += wsum[w];
        int excl = carry + prev + sc - v;
        if (i < NN) { rowstart[i] = excl; cursor[i] = excl; }
        __syncthreads();
        if (tid == 1023) carry_s = carry + prev + sc;
    }
    __syncthreads();
    if (tid == 0) rowstart[NN] = carry_s;
}

__global__ void scatter_kernel(const int* __restrict__ src, const int* __restrict__ dst,
                               int* __restrict__ cursor, unsigned short* __restrict__ cols) {
    int e = blockIdx.x * 256 + threadIdx.x;
    if (e < EE) {
        int p = atomicAdd(&cursor[dst[e]], 1);
        cols[p] = (unsigned short)src[e];   // NN < 65536
    }
}

// ---------------- aggregation v3: Aout[nid,256:512] = sum_{in-neighbors} Z[src,0:256]
// wave per (node, 64B column slice); slice = blockIdx.x & 7 -> round-robin XCD dispatch pins
// each slice (3.2 MB working set) to one XCD's 4 MB L2. 4 quarter-waves split the edge list,
// shfl_xor(16/32) reduce, 16 lanes store. list/cntp optional (selected-node variant).
__global__ void agg_kernel(const unsigned short* __restrict__ Z, unsigned short* __restrict__ Aout,
                           const int* __restrict__ rowstart, const unsigned short* __restrict__ cols,
                           const int* __restrict__ list, const int* __restrict__ cntp) {
    int slice = blockIdx.x & 7;
    int wave = threadIdx.x >> 6;
    int lane = threadIdx.x & 63;
    int idx = (blockIdx.x >> 3) * 4 + wave;
    int limit = cntp ? *cntp : NN;
    if (idx >= limit) return;                   // wave-uniform
    int nid = list ? list[idx] : idx;
    int q = lane >> 4, ql = lane & 15;
    int s = rowstart[nid], e = rowstart[nid + 1];
    float a0 = 0.f, a1 = 0.f;
    const unsigned short* zp = Z + slice * 32 + ql * 2;
    for (int i = s + q; i < e; i += 4) {
        int c = (int)__builtin_nontemporal_load(&cols[i]);
        ushort2 v = *(const ushort2*)(zp + (long)c * KD);
        a0 += bf2f(v.x);
        a1 += bf2f(v.y);
    }
    a0 += __shfl_xor(a0, 16, 64); a1 += __shfl_xor(a1, 16, 64);
    a0 += __shfl_xor(a0, 32, 64); a1 += __shfl_xor(a1, 32, 64);
    if (lane < 16) {
        ushort2 o;
        o.x = f2bf(a0); o.y = f2bf(a1);
        *(ushort2*)&Aout[(long)nid * KD + 256 + slice * 32 + lane * 2] = o;
    }
}

// ---------------- semantic router tail + softmax + top-2 + renormalize (wave per node)
__global__ void route_kernel(const unsigned short* __restrict__ T, const float* __restrict__ Ws2,
                             const float* __restrict__ bs2, const float* __restrict__ strug,
                             const int* __restrict__ batch, float* __restrict__ sparse) {
    int nid = blockIdx.x * 4 + (threadIdx.x >> 6);
    if (nid >= NN) return;
    int lane = threadIdx.x & 63;
    float s[8];
#pragma unroll
    for (int j = 0; j < 8; j++) s[j] = 0.f;
    ushort4 t4 = *(const ushort4*)&T[(long)nid * HH + lane * 4];
    float tv[4] = { bf2f(t4.x), bf2f(t4.y), bf2f(t4.z), bf2f(t4.w) };
#pragma unroll
    for (int kk = 0; kk < 4; kk++) {
        int k = lane * 4 + kk;
#pragma unroll
        for (int j = 0; j < 8; j++) s[j] += tv[kk] * Ws2[k * 8 + j];
    }
#pragma unroll
    for (int off = 32; off >= 1; off >>= 1) {
#pragma unroll
        for (int j = 0; j < 8; j++) s[j] += __shfl_xor(s[j], off, 64);
    }
    int g = batch[nid];
    float p[8], mx = -1e30f;
#pragma unroll
    for (int j = 0; j < 8; j++) {
        p[j] = 0.5f * (s[j] + bs2[j] + strug[g * 8 + j]);
        mx = fmaxf(mx, p[j]);
    }
    float ex[8];
#pragma unroll
    for (int j = 0; j < 8; j++) ex[j] = expf(p[j] - mx);
    int i1 = 0;
#pragma unroll
    for (int j = 1; j < 8; j++) if (ex[j] > ex[i1]) i1 = j;
    int i2 = (i1 == 0) ? 1 : 0;
#pragma unroll
    for (int j = 0; j < 8; j++) if (j != i1 && ex[j] > ex[i2]) i2 = j;
    float r = 1.f / (ex[i1] + ex[i2]);
    if (lane < 8)
        sparse[(long)nid * 8 + lane] = (lane == i1) ? ex[i1] * r : (lane == i2) ? ex[i2] * r : 0.f;
}

// ---------------- per-expert selected-node lists (top-2 sparsity)
__global__ void build_lists(const float* __restrict__ sparse, int* __restrict__ cnt,
                            int* __restrict__ lists) {
    int n = blockIdx.x * 256 + threadIdx.x;
    if (n >= NN) return;
#pragma unroll
    for (int e = 0; e < NEXP; e++) {
        if (sparse[n * 8 + e] > 0.f) {
            int p = atomicAdd(&cnt[e], 1);
            lists[(long)e * NN + p] = n;
        }
    }
}

// ---------------- MFMA GEMM: C[M,256] = A[M,K]_bf16 @ Bt[256,K]_bf16 (+bias)
// MODE 0: relu, store bf16 (stride ldz), rows 0..NN.
// MODE 1: rows from list (selected), out[n,:] += sparse[n,e] * val (fp32, pre-zeroed).
template <int MODE>
__global__ __launch_bounds__(256, 2) void gemm_kernel(
    const unsigned short* __restrict__ A, int lda, int K,
    const unsigned short* __restrict__ Bt, const float* __restrict__ bias,
    void* __restrict__ outp, int ldz,
    const float* __restrict__ sparse, int expert,
    const int* __restrict__ list, const int* __restrict__ cntp) {
    __shared__ __align__(16) unsigned short Alds[MT * LST];
    __shared__ __align__(16) unsigned short Blds[HH * LST];
    __shared__ int nodeids[MT];
    const int tid = threadIdx.x;
    const int wave = tid >> 6, lane = tid & 63;
    const int m = lane & 15, q = lane >> 4;
    const long row0 = (long)blockIdx.x * MT;

    if constexpr (MODE == 1) {
        int limit = *cntp;
        if (row0 >= limit) return;              // uniform exit
        if (tid < MT) {
            long rr = row0 + tid;
            nodeids[tid] = (rr < limit) ? list[rr] : -1;
        }
        __syncthreads();
    }

    f32x4 acc[2][16];
#pragma unroll
    for (int i = 0; i < 2; i++)
#pragma unroll
        for (int j = 0; j < 16; j++) acc[i][j] = (f32x4){0.f, 0.f, 0.f, 0.f};

    for (int k0 = 0; k0 < K; k0 += BK) {
#pragma unroll
        for (int i = 0; i < 4; i++) {          // stage A: 128 x 64
            int chunk = tid + 256 * i;
            int r = chunk >> 3, kc = (chunk & 7) << 3;
            u16x8 v = {0, 0, 0, 0, 0, 0, 0, 0};
            if constexpr (MODE == 0) {
                long grow = row0 + r;
                if (grow < NN) v = *(const u16x8*)&A[grow * lda + k0 + kc];
            } else {
                int nid2 = nodeids[r];
                if (nid2 >= 0) v = *(const u16x8*)&A[(long)nid2 * lda + k0 + kc];
            }
            *(u16x8*)&Alds[r * LST + kc] = v;
        }
#pragma unroll
        for (int i = 0; i < 8; i++) {          // stage Bt: 256 x 64 (k-contiguous rows)
            int chunk = tid + 256 * i;
            int nn2 = chunk >> 3, kc = (chunk & 7) << 3;
            u16x8 v = *(const u16x8*)&Bt[(long)nn2 * K + k0 + kc];
            *(u16x8*)&Blds[nn2 * LST + kc] = v;
        }
        __syncthreads();
#pragma unroll
        for (int kk = 0; kk < BK; kk += 32) {
            bf16x8 a0 = *(const bf16x8*)&Alds[(wave * 32 + m) * LST + kk + q * 8];
            bf16x8 a1 = *(const bf16x8*)&Alds[(wave * 32 + 16 + m) * LST + kk + q * 8];
#pragma unroll
            for (int ct = 0; ct < 16; ct++) {
                bf16x8 b = *(const bf16x8*)&Blds[(ct * 16 + m) * LST + kk + q * 8];
                acc[0][ct] = __builtin_amdgcn_mfma_f32_16x16x32_bf16(a0, b, acc[0][ct], 0, 0, 0);
                acc[1][ct] = __builtin_amdgcn_mfma_f32_16x16x32_bf16(a1, b, acc[1][ct], 0, 0, 0);
            }
        }
        __syncthreads();
    }
    // epilogue: D layout col = lane&15, row = (lane>>4)*4 + reg
#pragma unroll
    for (int mt = 0; mt < 2; mt++) {
        int rtile = wave * 32 + mt * 16 + q * 4;
        if constexpr (MODE == 0) {
            long rbase = row0 + rtile;
#pragma unroll
            for (int ct = 0; ct < 16; ct++) {
                int col = ct * 16 + m;
                float bv = bias[col];
#pragma unroll
                for (int r = 0; r < 4; r++) {
                    long grow = rbase + r;
                    if (grow < NN) {
                        float v = fmaxf(acc[mt][ct][r] + bv, 0.f);
                        ((unsigned short*)outp)[grow * ldz + col] = f2bf(v);
                    }
                }
            }
        } else {
            int nid4[4]; float w4[4];
#pragma unroll
            for (int r = 0; r < 4; r++) {
                nid4[r] = nodeids[rtile + r];
                w4[r] = (nid4[r] >= 0) ? sparse[(long)nid4[r] * 8 + expert] : 0.f;
            }
#pragma unroll
            for (int ct = 0; ct < 16; ct++) {
                int col = ct * 16 + m;
                float bv = bias[col];
#pragma unroll
                for (int r = 0; r < 4; r++) {
                    if (nid4[r] >= 0) {
                        float* o = (float*)outp + (long)nid4[r] * HH + col;
                        *o += w4[r] * (acc[mt][ct][r] + bv);
                    }
                }
            }
        }
    }
}

extern "C" void kernel_launch(void* const* d_in, const int* in_sizes, int n_in,
                              void* d_out, int out_size, void* d_ws, size_t ws_size,
                              hipStream_t stream) {
    const float* x     = (const float*)d_in[0];
    const int*   ei    = (const int*)d_in[1];
    const int*   src   = ei;
    const int*   dst   = ei + EE;
    const int*   batch = (const int*)d_in[2];
    const float* W_enc = (const float*)d_in[3];
    const float* b_enc = (const float*)d_in[4];
    const float* Ws1   = (const float*)d_in[5];
    const float* bs1   = (const float*)d_in[6];
    const float* Ws2   = (const float*)d_in[7];
    const float* bs2   = (const float*)d_in[8];
    const float* Wt1   = (const float*)d_in[9];
    const float* bt1   = (const float*)d_in[10];
    const float* Wt2   = (const float*)d_in[11];
    const float* bt2   = (const float*)d_in[12];
    const float* W_self  = (const float*)d_in[13];
    const float* W_neigh = (const float*)d_in[14];
    const float* b_exp   = (const float*)d_in[15];
    float* out = (float*)d_out;

    char* ws = (char*)d_ws;
    size_t off = 0;
    auto alloc = [&](size_t b) { size_t p = off; off = (off + b + 255) & ~(size_t)255; return p; };
    const size_t MPAD = 50048;  // 391 * 128

    unsigned short* Ash = (unsigned short*)(ws + alloc(MPAD * KD * 2));
    unsigned short* Ab0 = (unsigned short*)(ws + alloc(MPAD * KD * 2));
    unsigned short* Ab1 = (unsigned short*)(ws + alloc(MPAD * KD * 2));
    unsigned short* Tbuf = Ab1;  // alias: Tbuf consumed by route before Ab1 first written
    unsigned short* BtE = (unsigned short*)(ws + alloc((size_t)NEXP * LAY * HH * KD * 2));
    unsigned short* Bt1 = (unsigned short*)(ws + alloc((size_t)HH * HH * 2));
    float* sparse  = (float*)(ws + alloc((size_t)NN * 8 * 4));
    float* strug   = (float*)(ws + alloc((size_t)GG * 8 * 4));
    int* ncnt      = (int*)(ws + alloc((size_t)GG * 4));
    int* ecnt      = (int*)(ws + alloc((size_t)GG * 4));
    int* deg       = (int*)(ws + alloc((size_t)NN * 4));
    int* outdeg    = (int*)(ws + alloc((size_t)NN * 4));
    int* rowstart  = (int*)(ws + alloc((size_t)(NN + 1) * 4));
    int* cursor    = (int*)(ws + alloc((size_t)NN * 4));
    unsigned short* cols = (unsigned short*)(ws + alloc((size_t)EE * 2));
    int* lists     = (int*)(ws + alloc((size_t)NEXP * NN * 4));
    int* cnt8      = (int*)(ws + alloc((size_t)NEXP * 4));

    hipMemsetAsync(ncnt, 0, GG * 4, stream);
    hipMemsetAsync(ecnt, 0, GG * 4, stream);
    hipMemsetAsync(deg, 0, (size_t)NN * 4, stream);
    hipMemsetAsync(outdeg, 0, (size_t)NN * 4, stream);
    hipMemsetAsync(cnt8, 0, NEXP * 4, stream);
    hipMemsetAsync(out, 0, (size_t)NN * HH * 4, stream);

    pack_experts<<<NEXP * LAY * KD * HH / 256, 256, 0, stream>>>(W_self, W_neigh, BtE);
    pack_ws1<<<HH * HH / 256, 256, 0, stream>>>(Ws1, Bt1);
    encoder_kernel<<<NN, HH, 0, stream>>>(x, W_enc, b_enc, Ash);

    deg_kernel<<<(EE + 255) / 256, 256, 0, stream>>>(src, dst, deg, outdeg);
    hist_kernel<<<(NN + 255) / 256, 256, 0, stream>>>(batch, outdeg, ncnt, ecnt);
    scan_kernel<<<1, 1024, 0, stream>>>(deg, rowstart, cursor);
    scatter_kernel<<<(EE + 255) / 256, 256, 0, stream>>>(src, dst, cursor, cols);
    stru_kernel<<<GG, HH, 0, stream>>>(ncnt, ecnt, Wt1, bt1, Wt2, bt2, strug);

    const int GB = (NN + MT - 1) / MT;       // 391
    const int AGB = ((NN + 3) / 4) * 8;      // 100000 sliced agg blocks

    // semantic router hidden: T = relu(h @ Ws1 + bs1)
    gemm_kernel<0><<<GB, 256, 0, stream>>>(Ash, KD, HH, Bt1, bs1, Tbuf, HH, nullptr, 0,
                                           nullptr, nullptr);
    route_kernel<<<(NN + 3) / 4, 256, 0, stream>>>(Tbuf, Ws2, bs2, strug, batch, sparse);
    build_lists<<<(NN + 255) / 256, 256, 0, stream>>>(sparse, cnt8, lists);

    // shared layer-0 aggregation: Ash[:,256:512] = A . h  (reused by all 8 experts)
    agg_kernel<<<AGB, 256, 0, stream>>>(Ash, Ash, rowstart, cols, nullptr, nullptr);

    for (int e = 0; e < NEXP; e++) {
        const unsigned short* B0 = BtE + (size_t)(e * LAY + 0) * HH * KD;
        const unsigned short* B1 = BtE + (size_t)(e * LAY + 1) * HH * KD;
        const unsigned short* B2 = BtE + (size_t)(e * LAY + 2) * HH * KD;
        const float* bb = b_exp + (size_t)e * LAY * HH;
        const int* le = lists + (size_t)e * NN;
        gemm_kernel<0><<<GB, 256, 0, stream>>>(Ash, KD, KD, B0, bb, Ab0, KD, nullptr, 0,
                                               nullptr, nullptr);
        agg_kernel<<<AGB, 256, 0, stream>>>(Ab0, Ab0, rowstart, cols, nullptr, nullptr);
        gemm_kernel<0><<<GB, 256, 0, stream>>>(Ab0, KD, KD, B1, bb + HH, Ab1, KD, nullptr, 0,
                                               nullptr, nullptr);
        agg_kernel<<<AGB, 256, 0, stream>>>(Ab1, Ab1, rowstart, cols, le, cnt8 + e);
        gemm_kernel<1><<<GB, 256, 0, stream>>>(Ab1, KD, KD, B2, bb + 2 * HH, out, 0, sparse, e,
                                               le, cnt8 + e);
    }
}

// Round 4
// 2471.389 us; speedup vs baseline: 2.4309x; 2.4309x over previous
//
#include <hip/hip_runtime.h>
#include <hip/hip_bf16.h>

// GraphMoE dual router: encoder -> routers -> 8 GraphConv experts (3 layers) -> sparse combine.
// R1: agg latency fix (163->~100us): half-wave/node, 16B/lane, 4 gathers in flight.
// R2: XCD-sliced agg FAILED (FETCH unchanged 368MB, 435us — %8 XCD pinning not real; tiny
//     loads killed MLP). Kept: ushort cols, merged deg/hist, top-2 sparsity on layer-2.
// R3: revert agg to R1 design (ushort cols), unroll x8 (8 row-gathers in flight/half-wave);
//     same kernel handles selected-list variant for the 8 sparsified aggs.

#define NN 50000
#define EE 1600000
#define GG 64
#define HH 256
#define NEXP 8
#define LAY 3
#define KD 512          // concat K = [z | agg]
#define MT 128          // GEMM row tile per block
#define BK 64           // GEMM K tile
#define LST 72          // padded LDS stride (elements): 16B-aligned, bank-balanced

typedef __attribute__((ext_vector_type(8))) short bf16x8;
typedef __attribute__((ext_vector_type(8))) unsigned short u16x8;
typedef __attribute__((ext_vector_type(4))) float f32x4;

__device__ __forceinline__ float bf2f(unsigned short u) {
    union { unsigned int i; float f; } v; v.i = ((unsigned int)u) << 16; return v.f;
}
__device__ __forceinline__ unsigned short f2bf(float f) {
    union { unsigned int i; float f; } v; v.f = f;
    unsigned int r = (v.i + 0x7FFFu + ((v.i >> 16) & 1u)) >> 16;
    return (unsigned short)r;
}

// ---------------- encoder: h = relu(x[:,4:10] @ W_enc + b_enc), bf16 into Ash cols 0..255
__global__ void encoder_kernel(const float* __restrict__ x, const float* __restrict__ W,
                               const float* __restrict__ b, unsigned short* __restrict__ out) {
    int n = blockIdx.x, j = threadIdx.x;
    float acc = b[j];
#pragma unroll
    for (int i = 0; i < 6; i++) acc += x[n * 10 + 4 + i] * W[i * HH + j];
    acc = fmaxf(acc, 0.f);
    out[(long)n * KD + j] = f2bf(acc);
}

// ---------------- weight packing: Bt[(e*3+l)][n][k] bf16, k<256 -> W_self, k>=256 -> W_neigh
__global__ void pack_experts(const float* __restrict__ Wself, const float* __restrict__ Wneigh,
                             unsigned short* __restrict__ Bt) {
    int idx = blockIdx.x * 256 + threadIdx.x;          // (e,l,k,n), n fastest
    int n = idx & 255; int r = idx >> 8;
    int k = r & 511; r >>= 9;
    int l = r % LAY; int e = r / LAY;
    float v = (k < 256) ? Wself[(((e * LAY + l) * HH) + k) * HH + n]
                        : Wneigh[(((e * LAY + l) * HH) + (k - 256)) * HH + n];
    Bt[(((long)(e * LAY + l) * HH + n) * KD) + k] = f2bf(v);
}

__global__ void pack_ws1(const float* __restrict__ W, unsigned short* __restrict__ Bt) {
    int idx = blockIdx.x * 256 + threadIdx.x;
    int n = idx & 255; int k = idx >> 8;
    Bt[(long)n * HH + k] = f2bf(W[k * HH + n]);
}

// ---------------- degree pass: indeg (CSR rows) + outdeg (for per-graph edge histogram)
__global__ void deg_kernel(const int* __restrict__ src, const int* __restrict__ dst,
                           int* __restrict__ deg, int* __restrict__ outdeg) {
    int e = blockIdx.x * 256 + threadIdx.x;
    if (e < EE) {
        atomicAdd(&deg[dst[e]], 1);
        atomicAdd(&outdeg[src[e]], 1);
    }
}

// ---------------- per-graph node/edge histograms from sorted batch + outdeg (coalesced)
__global__ void hist_kernel(const int* __restrict__ batch, const int* __restrict__ outdeg,
                            int* __restrict__ ncnt, int* __restrict__ ecnt) {
    __shared__ int hn[GG], he[GG];
    if (threadIdx.x < GG) { hn[threadIdx.x] = 0; he[threadIdx.x] = 0; }
    __syncthreads();
    int i = blockIdx.x * 256 + threadIdx.x;
    if (i < NN) {
        int g = batch[i];
        atomicAdd(&hn[g], 1);
        atomicAdd(&he[g], outdeg[i]);
    }
    __syncthreads();
    if (threadIdx.x < GG) {
        if (hn[threadIdx.x]) atomicAdd(&ncnt[threadIdx.x], hn[threadIdx.x]);
        if (he[threadIdx.x]) atomicAdd(&ecnt[threadIdx.x], he[threadIdx.x]);
    }
}

// ---------------- structural router per graph: stru = relu(feat@Wt1+bt1)@Wt2+bt2
__global__ void stru_kernel(const int* __restrict__ ncnt, const int* __restrict__ ecnt,
                            const float* __restrict__ Wt1, const float* __restrict__ bt1,
                            const float* __restrict__ Wt2, const float* __restrict__ bt2,
                            float* __restrict__ strug) {
    __shared__ float t[HH];
    int g = blockIdx.x, j = threadIdx.x;
    float nf = log1pf((float)ncnt[g]);
    float ef = log1pf((float)ecnt[g]);
    float v = nf * Wt1[j] + ef * Wt1[HH + j] + bt1[j];
    t[j] = fmaxf(v, 0.f);
    __syncthreads();
    if (j < 8) {
        float sum = bt2[j];
        for (int k = 0; k < HH; k++) sum += t[k] * Wt2[k * 8 + j];
        strug[g * 8 + j] = sum;
    }
}

// single block, 1024 threads; shuffle-based inclusive scan, 2 barriers per 1024-chunk
__global__ void scan_kernel(const int* __restrict__ deg, int* __restrict__ rowstart,
                            int* __restrict__ cursor) {
    __shared__ int wsum[16];
    __shared__ int carry_s;
    int tid = threadIdx.x;
    int wid = tid >> 6, lane = tid & 63;
    if (tid == 0) carry_s = 0;
    __syncthreads();
    for (int base = 0; base < NN; base += 1024) {
        int i = base + tid;
        int v = (i < NN) ? deg[i] : 0;
        int sc = v;
#pragma unroll
        for (int off = 1; off < 64; off <<= 1) {
            int t = __shfl_up(sc, off, 64);
            if (lane >= off) sc += t;
        }
        if (lane == 63) wsum[wid] = sc;
        __syncthreads();
        int carry = carry_s;
        int prev = 0;
        for (int w = 0; w < wid; w++) prev += wsum[w];
        int excl = carry + prev + sc - v;
        if (i < NN) { rowstart[i] = excl; cursor[i] = excl; }
        __syncthreads();
        if (tid == 1023) carry_s = carry + prev + sc;
    }
    __syncthreads();
    if (tid == 0) rowstart[NN] = carry_s;
}

__global__ void scatter_kernel(const int* __restrict__ src, const int* __restrict__ dst,
                               int* __restrict__ cursor, unsigned short* __restrict__ cols) {
    int e = blockIdx.x * 256 + threadIdx.x;
    if (e < EE) {
        int p = atomicAdd(&cursor[dst[e]], 1);
        cols[p] = (unsigned short)src[e];   // NN < 65536
    }
}

// ---------------- aggregation (R1 design): Aout[nid,256:512] = sum_{in-nb} Z[src,0:256]
// half-wave (32 lanes) per node, 16B/lane (512B/row-gather), unroll x8 -> 8 independent
// row-gathers in flight per half-wave. fp32 acc, bf16 store. Optional selected-node list.
__global__ void agg_kernel(const unsigned short* __restrict__ Z, unsigned short* __restrict__ Aout,
                           const int* __restrict__ rowstart, const unsigned short* __restrict__ cols,
                           const int* __restrict__ list, const int* __restrict__ cntp) {
    int half = threadIdx.x >> 5;               // 0..7
    int lane = threadIdx.x & 31;
    int idx = blockIdx.x * 8 + half;
    int limit = cntp ? *cntp : NN;
    if (idx >= limit) return;                  // half-wave uniform
    int nid = list ? list[idx] : idx;
    int s = rowstart[nid], e = rowstart[nid + 1];
    float acc[8] = {0.f, 0.f, 0.f, 0.f, 0.f, 0.f, 0.f, 0.f};
    int i = s;
    for (; i + 8 <= e; i += 8) {
        int c[8];
#pragma unroll
        for (int u = 0; u < 8; u++) c[u] = (int)cols[i + u];
        u16x8 v[8];
#pragma unroll
        for (int u = 0; u < 8; u++) v[u] = *(const u16x8*)&Z[(long)c[u] * KD + lane * 8];
#pragma unroll
        for (int u = 0; u < 8; u++)
#pragma unroll
            for (int j = 0; j < 8; j++) acc[j] += bf2f(v[u][j]);
    }
    for (; i < e; i++) {
        int c = (int)cols[i];
        u16x8 v = *(const u16x8*)&Z[(long)c * KD + lane * 8];
#pragma unroll
        for (int j = 0; j < 8; j++) acc[j] += bf2f(v[j]);
    }
    u16x8 o;
#pragma unroll
    for (int j = 0; j < 8; j++) o[j] = f2bf(acc[j]);
    *(u16x8*)&Aout[(long)nid * KD + 256 + lane * 8] = o;
}

// ---------------- semantic router tail + softmax + top-2 + renormalize (wave per node)
__global__ void route_kernel(const unsigned short* __restrict__ T, const float* __restrict__ Ws2,
                             const float* __restrict__ bs2, const float* __restrict__ strug,
                             const int* __restrict__ batch, float* __restrict__ sparse) {
    int nid = blockIdx.x * 4 + (threadIdx.x >> 6);
    if (nid >= NN) return;
    int lane = threadIdx.x & 63;
    float s[8];
#pragma unroll
    for (int j = 0; j < 8; j++) s[j] = 0.f;
    ushort4 t4 = *(const ushort4*)&T[(long)nid * HH + lane * 4];
    float tv[4] = { bf2f(t4.x), bf2f(t4.y), bf2f(t4.z), bf2f(t4.w) };
#pragma unroll
    for (int kk = 0; kk < 4; kk++) {
        int k = lane * 4 + kk;
#pragma unroll
        for (int j = 0; j < 8; j++) s[j] += tv[kk] * Ws2[k * 8 + j];
    }
#pragma unroll
    for (int off = 32; off >= 1; off >>= 1) {
#pragma unroll
        for (int j = 0; j < 8; j++) s[j] += __shfl_xor(s[j], off, 64);
    }
    int g = batch[nid];
    float p[8], mx = -1e30f;
#pragma unroll
    for (int j = 0; j < 8; j++) {
        p[j] = 0.5f * (s[j] + bs2[j] + strug[g * 8 + j]);
        mx = fmaxf(mx, p[j]);
    }
    float ex[8];
#pragma unroll
    for (int j = 0; j < 8; j++) ex[j] = expf(p[j] - mx);
    int i1 = 0;
#pragma unroll
    for (int j = 1; j < 8; j++) if (ex[j] > ex[i1]) i1 = j;
    int i2 = (i1 == 0) ? 1 : 0;
#pragma unroll
    for (int j = 0; j < 8; j++) if (j != i1 && ex[j] > ex[i2]) i2 = j;
    float r = 1.f / (ex[i1] + ex[i2]);
    if (lane < 8)
        sparse[(long)nid * 8 + lane] = (lane == i1) ? ex[i1] * r : (lane == i2) ? ex[i2] * r : 0.f;
}

// ---------------- per-expert selected-node lists (top-2 sparsity)
__global__ void build_lists(const float* __restrict__ sparse, int* __restrict__ cnt,
                            int* __restrict__ lists) {
    int n = blockIdx.x * 256 + threadIdx.x;
    if (n >= NN) return;
#pragma unroll
    for (int e = 0; e < NEXP; e++) {
        if (sparse[n * 8 + e] > 0.f) {
            int p = atomicAdd(&cnt[e], 1);
            lists[(long)e * NN + p] = n;
        }
    }
}

// ---------------- MFMA GEMM: C[M,256] = A[M,K]_bf16 @ Bt[256,K]_bf16 (+bias)
// MODE 0: relu, store bf16 (stride ldz), rows 0..NN.
// MODE 1: rows from list (selected), out[n,:] += sparse[n,e] * val (fp32, pre-zeroed).
template <int MODE>
__global__ __launch_bounds__(256, 2) void gemm_kernel(
    const unsigned short* __restrict__ A, int lda, int K,
    const unsigned short* __restrict__ Bt, const float* __restrict__ bias,
    void* __restrict__ outp, int ldz,
    const float* __restrict__ sparse, int expert,
    const int* __restrict__ list, const int* __restrict__ cntp) {
    __shared__ __align__(16) unsigned short Alds[MT * LST];
    __shared__ __align__(16) unsigned short Blds[HH * LST];
    __shared__ int nodeids[MT];
    const int tid = threadIdx.x;
    const int wave = tid >> 6, lane = tid & 63;
    const int m = lane & 15, q = lane >> 4;
    const long row0 = (long)blockIdx.x * MT;

    if constexpr (MODE == 1) {
        int limit = *cntp;
        if (row0 >= limit) return;              // uniform exit
        if (tid < MT) {
            long rr = row0 + tid;
            nodeids[tid] = (rr < limit) ? list[rr] : -1;
        }
        __syncthreads();
    }

    f32x4 acc[2][16];
#pragma unroll
    for (int i = 0; i < 2; i++)
#pragma unroll
        for (int j = 0; j < 16; j++) acc[i][j] = (f32x4){0.f, 0.f, 0.f, 0.f};

    for (int k0 = 0; k0 < K; k0 += BK) {
#pragma unroll
        for (int i = 0; i < 4; i++) {          // stage A: 128 x 64
            int chunk = tid + 256 * i;
            int r = chunk >> 3, kc = (chunk & 7) << 3;
            u16x8 v = {0, 0, 0, 0, 0, 0, 0, 0};
            if constexpr (MODE == 0) {
                long grow = row0 + r;
                if (grow < NN) v = *(const u16x8*)&A[grow * lda + k0 + kc];
            } else {
                int nid2 = nodeids[r];
                if (nid2 >= 0) v = *(const u16x8*)&A[(long)nid2 * lda + k0 + kc];
            }
            *(u16x8*)&Alds[r * LST + kc] = v;
        }
#pragma unroll
        for (int i = 0; i < 8; i++) {          // stage Bt: 256 x 64 (k-contiguous rows)
            int chunk = tid + 256 * i;
            int nn2 = chunk >> 3, kc = (chunk & 7) << 3;
            u16x8 v = *(const u16x8*)&Bt[(long)nn2 * K + k0 + kc];
            *(u16x8*)&Blds[nn2 * LST + kc] = v;
        }
        __syncthreads();
#pragma unroll
        for (int kk = 0; kk < BK; kk += 32) {
            bf16x8 a0 = *(const bf16x8*)&Alds[(wave * 32 + m) * LST + kk + q * 8];
            bf16x8 a1 = *(const bf16x8*)&Alds[(wave * 32 + 16 + m) * LST + kk + q * 8];
#pragma unroll
            for (int ct = 0; ct < 16; ct++) {
                bf16x8 b = *(const bf16x8*)&Blds[(ct * 16 + m) * LST + kk + q * 8];
                acc[0][ct] = __builtin_amdgcn_mfma_f32_16x16x32_bf16(a0, b, acc[0][ct], 0, 0, 0);
                acc[1][ct] = __builtin_amdgcn_mfma_f32_16x16x32_bf16(a1, b, acc[1][ct], 0, 0, 0);
            }
        }
        __syncthreads();
    }
    // epilogue: D layout col = lane&15, row = (lane>>4)*4 + reg
#pragma unroll
    for (int mt = 0; mt < 2; mt++) {
        int rtile = wave * 32 + mt * 16 + q * 4;
        if constexpr (MODE == 0) {
            long rbase = row0 + rtile;
#pragma unroll
            for (int ct = 0; ct < 16; ct++) {
                int col = ct * 16 + m;
                float bv = bias[col];
#pragma unroll
                for (int r = 0; r < 4; r++) {
                    long grow = rbase + r;
                    if (grow < NN) {
                        float v = fmaxf(acc[mt][ct][r] + bv, 0.f);
                        ((unsigned short*)outp)[grow * ldz + col] = f2bf(v);
                    }
                }
            }
        } else {
            int nid4[4]; float w4[4];
#pragma unroll
            for (int r = 0; r < 4; r++) {
                nid4[r] = nodeids[rtile + r];
                w4[r] = (nid4[r] >= 0) ? sparse[(long)nid4[r] * 8 + expert] : 0.f;
            }
#pragma unroll
            for (int ct = 0; ct < 16; ct++) {
                int col = ct * 16 + m;
                float bv = bias[col];
#pragma unroll
                for (int r = 0; r < 4; r++) {
                    if (nid4[r] >= 0) {
                        float* o = (float*)outp + (long)nid4[r] * HH + col;
                        *o += w4[r] * (acc[mt][ct][r] + bv);
                    }
                }
            }
        }
    }
}

extern "C" void kernel_launch(void* const* d_in, const int* in_sizes, int n_in,
                              void* d_out, int out_size, void* d_ws, size_t ws_size,
                              hipStream_t stream) {
    const float* x     = (const float*)d_in[0];
    const int*   ei    = (const int*)d_in[1];
    const int*   src   = ei;
    const int*   dst   = ei + EE;
    const int*   batch = (const int*)d_in[2];
    const float* W_enc = (const float*)d_in[3];
    const float* b_enc = (const float*)d_in[4];
    const float* Ws1   = (const float*)d_in[5];
    const float* bs1   = (const float*)d_in[6];
    const float* Ws2   = (const float*)d_in[7];
    const float* bs2   = (const float*)d_in[8];
    const float* Wt1   = (const float*)d_in[9];
    const float* bt1   = (const float*)d_in[10];
    const float* Wt2   = (const float*)d_in[11];
    const float* bt2   = (const float*)d_in[12];
    const float* W_self  = (const float*)d_in[13];
    const float* W_neigh = (const float*)d_in[14];
    const float* b_exp   = (const float*)d_in[15];
    float* out = (float*)d_out;

    char* ws = (char*)d_ws;
    size_t off = 0;
    auto alloc = [&](size_t b) { size_t p = off; off = (off + b + 255) & ~(size_t)255; return p; };
    const size_t MPAD = 50048;  // 391 * 128

    unsigned short* Ash = (unsigned short*)(ws + alloc(MPAD * KD * 2));
    unsigned short* Ab0 = (unsigned short*)(ws + alloc(MPAD * KD * 2));
    unsigned short* Ab1 = (unsigned short*)(ws + alloc(MPAD * KD * 2));
    unsigned short* Tbuf = Ab1;  // alias: Tbuf consumed by route before Ab1 first written
    unsigned short* BtE = (unsigned short*)(ws + alloc((size_t)NEXP * LAY * HH * KD * 2));
    unsigned short* Bt1 = (unsigned short*)(ws + alloc((size_t)HH * HH * 2));
    float* sparse  = (float*)(ws + alloc((size_t)NN * 8 * 4));
    float* strug   = (float*)(ws + alloc((size_t)GG * 8 * 4));
    int* ncnt      = (int*)(ws + alloc((size_t)GG * 4));
    int* ecnt      = (int*)(ws + alloc((size_t)GG * 4));
    int* deg       = (int*)(ws + alloc((size_t)NN * 4));
    int* outdeg    = (int*)(ws + alloc((size_t)NN * 4));
    int* rowstart  = (int*)(ws + alloc((size_t)(NN + 1) * 4));
    int* cursor    = (int*)(ws + alloc((size_t)NN * 4));
    unsigned short* cols = (unsigned short*)(ws + alloc((size_t)EE * 2));
    int* lists     = (int*)(ws + alloc((size_t)NEXP * NN * 4));
    int* cnt8      = (int*)(ws + alloc((size_t)NEXP * 4));

    hipMemsetAsync(ncnt, 0, GG * 4, stream);
    hipMemsetAsync(ecnt, 0, GG * 4, stream);
    hipMemsetAsync(deg, 0, (size_t)NN * 4, stream);
    hipMemsetAsync(outdeg, 0, (size_t)NN * 4, stream);
    hipMemsetAsync(cnt8, 0, NEXP * 4, stream);
    hipMemsetAsync(out, 0, (size_t)NN * HH * 4, stream);

    pack_experts<<<NEXP * LAY * KD * HH / 256, 256, 0, stream>>>(W_self, W_neigh, BtE);
    pack_ws1<<<HH * HH / 256, 256, 0, stream>>>(Ws1, Bt1);
    encoder_kernel<<<NN, HH, 0, stream>>>(x, W_enc, b_enc, Ash);

    deg_kernel<<<(EE + 255) / 256, 256, 0, stream>>>(src, dst, deg, outdeg);
    hist_kernel<<<(NN + 255) / 256, 256, 0, stream>>>(batch, outdeg, ncnt, ecnt);
    scan_kernel<<<1, 1024, 0, stream>>>(deg, rowstart, cursor);
    scatter_kernel<<<(EE + 255) / 256, 256, 0, stream>>>(src, dst, cursor, cols);
    stru_kernel<<<GG, HH, 0, stream>>>(ncnt, ecnt, Wt1, bt1, Wt2, bt2, strug);

    const int GB = (NN + MT - 1) / MT;       // 391
    const int AGB = NN / 8;                  // 6250 agg blocks (8 half-waves each)

    // semantic router hidden: T = relu(h @ Ws1 + bs1)
    gemm_kernel<0><<<GB, 256, 0, stream>>>(Ash, KD, HH, Bt1, bs1, Tbuf, HH, nullptr, 0,
                                           nullptr, nullptr);
    route_kernel<<<(NN + 3) / 4, 256, 0, stream>>>(Tbuf, Ws2, bs2, strug, batch, sparse);
    build_lists<<<(NN + 255) / 256, 256, 0, stream>>>(sparse, cnt8, lists);

    // shared layer-0 aggregation: Ash[:,256:512] = A . h  (reused by all 8 experts)
    agg_kernel<<<AGB, 256, 0, stream>>>(Ash, Ash, rowstart, cols, nullptr, nullptr);

    for (int e = 0; e < NEXP; e++) {
        const unsigned short* B0 = BtE + (size_t)(e * LAY + 0) * HH * KD;
        const unsigned short* B1 = BtE + (size_t)(e * LAY + 1) * HH * KD;
        const unsigned short* B2 = BtE + (size_t)(e * LAY + 2) * HH * KD;
        const float* bb = b_exp + (size_t)e * LAY * HH;
        const int* le = lists + (size_t)e * NN;
        gemm_kernel<0><<<GB, 256, 0, stream>>>(Ash, KD, KD, B0, bb, Ab0, KD, nullptr, 0,
                                               nullptr, nullptr);
        agg_kernel<<<AGB, 256, 0, stream>>>(Ab0, Ab0, rowstart, cols, nullptr, nullptr);
        gemm_kernel<0><<<GB, 256, 0, stream>>>(Ab0, KD, KD, B1, bb + HH, Ab1, KD, nullptr, 0,
                                               nullptr, nullptr);
        agg_kernel<<<AGB, 256, 0, stream>>>(Ab1, Ab1, rowstart, cols, le, cnt8 + e);
        gemm_kernel<1><<<GB, 256, 0, stream>>>(Ab1, KD, KD, B2, bb + 2 * HH, out, 0, sparse, e,
                                               le, cnt8 + e);
    }
}